// Round 20
// baseline (147.292 us; speedup 1.0000x reference)
//
#include <hip/hip_runtime.h>

#define NB 64
#define SS 512
#define HIDD 256
#define NHEADS 4
#define ADIM 64
#define NTOT 576   // Wq(256) + Wk(256) + Wv(64) concatenated output cols

typedef __attribute__((ext_vector_type(8))) short short8v;
typedef __attribute__((ext_vector_type(4))) float f32x4;

#define MFMA16(A, B, C) __builtin_amdgcn_mfma_f32_16x16x32_bf16(A, B, C, 0, 0, 0)
#define AS1 __attribute__((address_space(1)))
#define AS3 __attribute__((address_space(3)))

// async 16B/lane global->LDS copy (dest = wave-uniform base + lane*16)
__device__ __forceinline__ void g2l16(void* lds, const void* g) {
    __builtin_amdgcn_global_load_lds((const AS1 unsigned*)g,
                                     (AS3 unsigned*)lds, 16, 0, 0);
}

// split fp32 x into bf16 hi + bf16 lo with x ~= hi + lo (error ~2^-17 rel)
__device__ __forceinline__ void bsplit(float x, short& hi, short& lo) {
    unsigned u = __float_as_uint(x);
    unsigned uh = (u + 0x8000u) & 0xFFFF0000u;
    hi = (short)(uh >> 16);
    float r = x - __uint_as_float(uh);
    lo = (short)((__float_as_uint(r) + 0x8000u) >> 16);
}

__device__ __forceinline__ void bsplit_v(float x, short8v& vh, short8v& vl, int i) {
    short h, l;
    bsplit(x, h, l);
    vh[i] = h;
    vl[i] = l;
}

// round-to-nearest fp32 -> bf16 (single)
__device__ __forceinline__ short bf16r(float x) {
    return (short)((__float_as_uint(x) + 0x8000u) >> 16);
}

// fragment-tiled Q/K address: [b][h][t16][ks2][lane][8], lane = rk + 16*lgk
__device__ __forceinline__ int frag_addr(int bb, int hh, int s, int d) {
    const int t16 = s >> 4, rk = s & 15;
    const int ks2 = d >> 5, lgk = (d >> 3) & 3, e8 = d & 7;
    return ((((bb * 4 + hh) * 32 + t16) * 2 + ks2) * 64 + rk + 16 * lgk) * 8 + e8;
}

// ---------------------------------------------------------------------------
// Pre-split + transpose weights. Blocks 0..575: WT[n][k] hi/lo for {Wq|Wk|Wv}.
// Blocks 576..639: WhT[n][d] single-bf16 (Wh transposed).
// ---------------------------------------------------------------------------
__global__ __launch_bounds__(256) void prep_weights(
    const float* __restrict__ Wq, const float* __restrict__ Wk,
    const float* __restrict__ Wv, const float* __restrict__ Wh,
    short* __restrict__ WT_hi, short* __restrict__ WT_lo,
    short* __restrict__ WhT)
{
    const int bx = blockIdx.x;
    if (bx < NTOT) {
        const int idx = bx * 256 + threadIdx.x;   // 576*256 elements
        const int n = idx >> 8, k = idx & 255;
        float v;
        if (n < 256)      v = Wq[k * 256 + n];
        else if (n < 512) v = Wk[k * 256 + (n - 256)];
        else              v = Wv[k * 64 + (n - 512)];
        short h, l;
        bsplit(v, h, l);
        WT_hi[idx] = h;
        WT_lo[idx] = l;
    } else {
        const int idx2 = (bx - NTOT) * 256 + threadIdx.x;  // 256*64 elements
        const int n = idx2 >> 6, d = idx2 & 63;
        WhT[idx2] = bf16r(Wh[d * HIDD + n]);
    }
}

// ---------------------------------------------------------------------------
// Q/K projection (MFMA split-bf16, 3-term internally). Block = 64 m-rows x
// 128 n-cols: y = {0,1} -> Q halves, {2,3} -> K halves. LDS 32KB (4 blk/CU).
// A-frags in registers (prefetched); WT chunk (128x32 hi+lo) dbuf LDS-DMA.
// Output: single-bf16 frag tiles (QK^T consumer is single-bf16).
// ---------------------------------------------------------------------------
__global__ __launch_bounds__(256) void qkv_qk(
    const float* __restrict__ query, const float* __restrict__ key,
    const short* __restrict__ WT_hi, const short* __restrict__ WT_lo,
    const float* __restrict__ bq, const float* __restrict__ bk,
    short* __restrict__ Qhi, short* __restrict__ Khi)
{
    __shared__ short Ws_h[2][128 * 32];   // 8 KB per buffer
    __shared__ short Ws_l[2][128 * 32];   // 8 KB per buffer

    const int bm = blockIdx.x * 64;
    const int y = blockIdx.y;             // 0,1 = Q halves; 2,3 = K halves
    const int t = y >> 1;                 // 0 = Q, 1 = K
    const int half = y & 1;
    const int nrow0 = t * 256 + half * 128;   // row base in WT
    const float* A = t ? key : query;
    const float* biasp = t ? bk : bq;
    short* Dhi = t ? Khi : Qhi;

    const int tid = threadIdx.x;
    const int w = tid >> 6, l = tid & 63;
    const int l15 = l & 15, lg = l >> 4;
    const int wbase = tid & 192;          // wave-uniform

    auto stageWT = [&](int buf, int kc) {
#pragma unroll
        for (int i = 0; i < 2; ++i) {
            const int g = i * 256 + tid;          // chunk id 0..511
            const int row = g >> 2;               // 0..127
            const int p = g & 3;
            const int sl = p ^ (row & 3);
            const size_t goff = (size_t)(nrow0 + row) * HIDD + kc * 32 + sl * 8;
            g2l16(&Ws_h[buf][(i * 256 + wbase) * 8], WT_hi + goff);
            g2l16(&Ws_l[buf][(i * 256 + wbase) * 8], WT_lo + goff);
        }
    };

    const float* arow = A + (size_t)(bm + w * 16 + l15) * HIDD + lg * 8;

    f32x4 acc[8];
#pragma unroll
    for (int jn = 0; jn < 8; ++jn) acc[jn] = (f32x4){0.f, 0.f, 0.f, 0.f};

    float4 a0c = *reinterpret_cast<const float4*>(arow);
    float4 a1c = *reinterpret_cast<const float4*>(arow + 4);
    stageWT(0, 0);
    __syncthreads();   // WT[0] ready (vmcnt drained)

    int cur = 0;
#pragma unroll
    for (int kc = 0; kc < 8; ++kc) {
        float4 a0n, a1n;
        if (kc < 7) {
            a0n = *reinterpret_cast<const float4*>(arow + (kc + 1) * 32);
            a1n = *reinterpret_cast<const float4*>(arow + (kc + 1) * 32 + 4);
            stageWT(cur ^ 1, kc + 1);   // DMA overlaps this iter's compute
        }

        short8v ah, al;
        bsplit_v(a0c.x, ah, al, 0);
        bsplit_v(a0c.y, ah, al, 1);
        bsplit_v(a0c.z, ah, al, 2);
        bsplit_v(a0c.w, ah, al, 3);
        bsplit_v(a1c.x, ah, al, 4);
        bsplit_v(a1c.y, ah, al, 5);
        bsplit_v(a1c.z, ah, al, 6);
        bsplit_v(a1c.w, ah, al, 7);

#pragma unroll
        for (int jn = 0; jn < 8; ++jn) {
            const int rowB = jn * 16 + l15;
            const int c = lg ^ (rowB & 3);
            short8v bh = *reinterpret_cast<const short8v*>(&Ws_h[cur][rowB * 32 + c * 8]);
            short8v bl = *reinterpret_cast<const short8v*>(&Ws_l[cur][rowB * 32 + c * 8]);
            acc[jn] = MFMA16(ah, bh, acc[jn]);
            acc[jn] = MFMA16(ah, bl, acc[jn]);
            acc[jn] = MFMA16(al, bh, acc[jn]);
        }
        __syncthreads();   // readers done with cur; prefetch landed
        cur ^= 1;
        if (kc < 7) { a0c = a0n; a1c = a1n; }
    }

    // ---- epilogue: bias + fragment-tiled single-bf16 scatter ----
#pragma unroll
    for (int jn = 0; jn < 8; ++jn) {
        const int ncol = half * 128 + jn * 16 + l15;   // 0..255 within tensor
        const float bias = biasp[ncol];
        const int hh = ncol >> 6, dd = ncol & 63;
#pragma unroll
        for (int r = 0; r < 4; ++r) {
            const int m = bm + w * 16 + lg * 4 + r;
            const int bb = m >> 9, s = m & 511;
            const int fa = frag_addr(bb, hh, s, dd);
            Dhi[fa] = bf16r(acc[jn][r] + bias);
        }
    }
}

// ---------------------------------------------------------------------------
// V projection -> V^T bf16 fragment tiles: VT[b][dt(4)][ks(16)][lane(64)][8]
// ---------------------------------------------------------------------------
__global__ __launch_bounds__(256) void qkv_v(
    const float* __restrict__ value,
    const short* __restrict__ WT_hi, const short* __restrict__ WT_lo,
    const float* __restrict__ bv, short* __restrict__ VT)
{
    __shared__ short Ws_h[2][64 * 32];    // 4 KB per buffer
    __shared__ short Ws_l[2][64 * 32];

    const int bm = blockIdx.x * 64;
    const int tid = threadIdx.x;
    const int w = tid >> 6, l = tid & 63;
    const int l15 = l & 15, lg = l >> 4;
    const int wbase = tid & 192;

    auto stageWT = [&](int buf, int kc) {
        const int row = tid >> 2;             // 0..63
        const int p = tid & 3;
        const int sl = p ^ (row & 3);
        const size_t goff = (size_t)(512 + row) * HIDD + kc * 32 + sl * 8;
        g2l16(&Ws_h[buf][wbase * 8], WT_hi + goff);
        g2l16(&Ws_l[buf][wbase * 8], WT_lo + goff);
    };

    const float* arow = value + (size_t)(bm + w * 16 + l15) * HIDD + lg * 8;

    f32x4 acc[4];
#pragma unroll
    for (int jn = 0; jn < 4; ++jn) acc[jn] = (f32x4){0.f, 0.f, 0.f, 0.f};

    float4 a0c = *reinterpret_cast<const float4*>(arow);
    float4 a1c = *reinterpret_cast<const float4*>(arow + 4);
    stageWT(0, 0);
    __syncthreads();

    int cur = 0;
#pragma unroll
    for (int kc = 0; kc < 8; ++kc) {
        float4 a0n, a1n;
        if (kc < 7) {
            a0n = *reinterpret_cast<const float4*>(arow + (kc + 1) * 32);
            a1n = *reinterpret_cast<const float4*>(arow + (kc + 1) * 32 + 4);
            stageWT(cur ^ 1, kc + 1);
        }

        short8v ah, al;
        bsplit_v(a0c.x, ah, al, 0);
        bsplit_v(a0c.y, ah, al, 1);
        bsplit_v(a0c.z, ah, al, 2);
        bsplit_v(a0c.w, ah, al, 3);
        bsplit_v(a1c.x, ah, al, 4);
        bsplit_v(a1c.y, ah, al, 5);
        bsplit_v(a1c.z, ah, al, 6);
        bsplit_v(a1c.w, ah, al, 7);

#pragma unroll
        for (int jn = 0; jn < 4; ++jn) {
            const int rowB = jn * 16 + l15;
            const int c = lg ^ (rowB & 3);
            short8v bh = *reinterpret_cast<const short8v*>(&Ws_h[cur][rowB * 32 + c * 8]);
            short8v bl = *reinterpret_cast<const short8v*>(&Ws_l[cur][rowB * 32 + c * 8]);
            acc[jn] = MFMA16(ah, bh, acc[jn]);
            acc[jn] = MFMA16(ah, bl, acc[jn]);
            acc[jn] = MFMA16(al, bh, acc[jn]);
        }
        __syncthreads();
        cur ^= 1;
        if (kc < 7) { a0c = a0n; a1c = a1n; }
    }

    // ---- epilogue: V^T bf16 frag-tile scatter ----
#pragma unroll
    for (int jn = 0; jn < 4; ++jn) {
        const int d = jn * 16 + l15;
        const float bias = bv[d];
#pragma unroll
        for (int r = 0; r < 4; ++r) {
            const int m = bm + w * 16 + lg * 4 + r;
            const int bb = m >> 9, kk = m & 511;
            const int ks = kk >> 5;
            const int lane = l15 + 16 * ((kk >> 3) & 3);
            const int idx = (((bb * 4 + jn) * 16 + ks) * 64 + lane) * 8 + (kk & 7);
            VT[idx] = bf16r(acc[jn][r] + bias);
        }
    }
}

// ---------------------------------------------------------------------------
// FUSED attention, 4 waves x 16 q-rows (2048 blocks). Wave w owns k-quarter
// kt = w. ALL 16 K-fragments of a head are loaded into registers FIRST
// (16-deep in-flight batch; r19's VGPR-60 build serialized these 4-deep and
// exposed ~4x L2 latency per head), then 16 MFMAs, then softmax. Coalesced
// LDS-staged writeout for attn and out. QK^T single bf16.
// ---------------------------------------------------------------------------
__global__ __launch_bounds__(256) void attn_probs_fused(
    const short* __restrict__ Qhi_g, const short* __restrict__ Khi_g,
    const short* __restrict__ VT, const short* __restrict__ WhT,
    const int* __restrict__ mask, const float* __restrict__ bh,
    float* __restrict__ attn, float* __restrict__ out)
{
    __shared__ __align__(16) float As[16 * 516];   // 33KB attn tile; aliased later
    __shared__ float red[2][4][16];

    // bijective XCD swizzle: 2048 blocks = 8 xcds x 256
    const int wg = blockIdx.x;
    const int swz = (wg & 7) * 256 + (wg >> 3);
    const int b = swz >> 5;
    const int qt_base = swz & 31;         // q-tile16 index
    const int q0 = qt_base * 16;

    const int tid = threadIdx.x;
    const int w = tid >> 6;               // 0..3 -> k-quarter kt = w
    const int l = tid & 63;
    const int l15 = l & 15;
    const int lg = l >> 4;

    // ---- pack mask bits: lane row q0+l15; 8 subtiles x 4 k-bits = 32 bits ----
    unsigned mbits = 0;
    {
        const int q = q0 + l15;
        const int* mrow = mask + ((size_t)b * SS + q) * SS;
        int4 mv[8];
#pragma unroll
        for (int ms = 0; ms < 8; ++ms)
            mv[ms] = *reinterpret_cast<const int4*>(&mrow[w * 128 + ms * 16 + lg * 4]);
#pragma unroll
        for (int ms = 0; ms < 8; ++ms) {
            mbits |= (mv[ms].x != 0 ? 1u : 0u) << (ms * 4 + 0);
            mbits |= (mv[ms].y != 0 ? 1u : 0u) << (ms * 4 + 1);
            mbits |= (mv[ms].z != 0 ? 1u : 0u) << (ms * 4 + 2);
            mbits |= (mv[ms].w != 0 ? 1u : 0u) << (ms * 4 + 3);
        }
    }

    f32x4 acc[8];
#pragma unroll
    for (int ms = 0; ms < 8; ++ms) acc[ms] = (f32x4){0.f, 0.f, 0.f, 0.f};

    for (int h = 0; h < NHEADS; ++h) {
        const int bh32 = (b * 4 + h) * 32;

        // ---- batch-load ALL fragments for this head into registers ----
        short8v qh[2];
        short8v kf[8][2];
#pragma unroll
        for (int ks2 = 0; ks2 < 2; ++ks2) {
            const int off = (((bh32 + qt_base) * 2 + ks2) * 64 + l) * 8;
            qh[ks2] = *reinterpret_cast<const short8v*>(Qhi_g + off);
        }
#pragma unroll
        for (int ms = 0; ms < 8; ++ms) {
            const int t16 = w * 8 + ms;
#pragma unroll
            for (int ks2 = 0; ks2 < 2; ++ks2) {
                const int base = (((bh32 + t16) * 2 + ks2) * 64 + l) * 8;
                kf[ms][ks2] = *reinterpret_cast<const short8v*>(Khi_g + base);
            }
        }

        f32x4 e[8];
#pragma unroll
        for (int ms = 0; ms < 8; ++ms) e[ms] = (f32x4){0.f, 0.f, 0.f, 0.f};

#pragma unroll
        for (int ms = 0; ms < 8; ++ms) {
            e[ms] = MFMA16(kf[ms][0], qh[0], e[ms]);
            e[ms] = MFMA16(kf[ms][1], qh[1], e[ms]);
        }

        // ---- masked exp (no max shift) + sum + head-mean accumulate ----
        float sm = 0.f;
        const float c = 0.125f;
#pragma unroll
        for (int ms = 0; ms < 8; ++ms)
#pragma unroll
            for (int r = 0; r < 4; ++r) {
                float p = __expf(e[ms][r] * c);
                const unsigned bit = (mbits >> (ms * 4 + r)) & 1u;
                p = bit ? p : 0.f;
                e[ms][r] = p;
                sm += p;
            }
        sm += __shfl_xor(sm, 16);
        sm += __shfl_xor(sm, 32);
        if (l < 16) red[h & 1][w][l] = sm;
        __syncthreads();
        {
            const float Z = (red[h & 1][0][l15] + red[h & 1][1][l15]) +
                            (red[h & 1][2][l15] + red[h & 1][3][l15]);
            const float inv = 0.25f / fmaxf(Z, 1e-30f);
#pragma unroll
            for (int ms = 0; ms < 8; ++ms)
#pragma unroll
                for (int r = 0; r < 4; ++r)
                    acc[ms][r] += e[ms][r] * inv;
        }
    }

    // ---- stage attn tile in LDS (f32) ----
#pragma unroll
    for (int ms = 0; ms < 8; ++ms) {
        const int k = w * 128 + ms * 16 + lg * 4;
        float4 o;
        o.x = acc[ms][0];
        o.y = acc[ms][1];
        o.z = acc[ms][2];
        o.w = acc[ms][3];
        *reinterpret_cast<float4*>(&As[l15 * 516 + k]) = o;
    }
    __syncthreads();

    // ---- COALESCED attn writeout: 16 rows x 512 f32, 16B/lane linear ----
    {
        float* attn_base = attn + ((size_t)b * SS + q0) * SS;
#pragma unroll
        for (int i = 0; i < 8; ++i) {
            const int g = i * 256 + tid;
            const int row = g >> 7, u = g & 127;
            float4 v = *reinterpret_cast<const float4*>(&As[row * 516 + u * 4]);
            *reinterpret_cast<float4*>(attn_base + (size_t)row * SS + u * 4) = v;
        }
    }

    // ---- PV: T^T[d][q] = sum_k V^T[d][k] P[k][q]; wave w owns d-tile w ----
    f32x4 tacc = (f32x4){0.f, 0.f, 0.f, 0.f};
#pragma unroll
    for (int ks = 0; ks < 16; ++ks) {
        short8v va = *reinterpret_cast<const short8v*>(
            VT + (((b * 4 + w) * 16 + ks) * 64 + l) * 8);
        float4 p0 = *reinterpret_cast<const float4*>(&As[l15 * 516 + ks * 32 + lg * 8]);
        float4 p1 = *reinterpret_cast<const float4*>(&As[l15 * 516 + ks * 32 + lg * 8 + 4]);
        short8v pb;
        pb[0] = bf16r(p0.x);
        pb[1] = bf16r(p0.y);
        pb[2] = bf16r(p0.z);
        pb[3] = bf16r(p0.w);
        pb[4] = bf16r(p1.x);
        pb[5] = bf16r(p1.y);
        pb[6] = bf16r(p1.z);
        pb[7] = bf16r(p1.w);
        tacc = MFMA16(va, pb, tacc);
    }
    __syncthreads();   // all As reads done before aliasing as T_s

    // ---- T -> LDS f32 (alias of As): T_s[q][68], q 0..15, d 0..63 ----
    float* T_s = As;
    {
        const int q = l15;
        const int d = w * 16 + lg * 4;
        float4 tv;
        tv.x = tacc[0];
        tv.y = tacc[1];
        tv.z = tacc[2];
        tv.w = tacc[3];
        *reinterpret_cast<float4*>(&T_s[q * 68 + d]) = tv;
    }
    __syncthreads();

    // ---- TWh: out[q][n] = sum_d T[q][d] Wh[d][n] + bh; wave w: n-tiles 4w..4w+3
    f32x4 oacc[4];
#pragma unroll
    for (int nt = 0; nt < 4; ++nt) oacc[nt] = (f32x4){0.f, 0.f, 0.f, 0.f};

#pragma unroll
    for (int ks = 0; ks < 2; ++ks) {
        short8v ta;
        {
            const int q = l15;
            float4 t0 = *reinterpret_cast<const float4*>(&T_s[q * 68 + ks * 32 + lg * 8]);
            float4 t1 = *reinterpret_cast<const float4*>(&T_s[q * 68 + ks * 32 + lg * 8 + 4]);
            ta[0] = bf16r(t0.x);
            ta[1] = bf16r(t0.y);
            ta[2] = bf16r(t0.z);
            ta[3] = bf16r(t0.w);
            ta[4] = bf16r(t1.x);
            ta[5] = bf16r(t1.y);
            ta[6] = bf16r(t1.z);
            ta[7] = bf16r(t1.w);
        }
#pragma unroll
        for (int nt = 0; nt < 4; ++nt) {
            const int n = (w * 4 + nt) * 16 + l15;
            short8v wb = *reinterpret_cast<const short8v*>(
                WhT + n * 64 + ks * 32 + lg * 8);
            oacc[nt] = MFMA16(ta, wb, oacc[nt]);
        }
    }

    // ---- stage out tile (with bias) in LDS: Os[q][260] at As+1536 ----
    float* Os = As + 1536;   // past T_s region (1088 floats), 16B aligned
#pragma unroll
    for (int nt = 0; nt < 4; ++nt) {
        const int n = (w * 4 + nt) * 16 + l15;
        const float bias = bh[n];
#pragma unroll
        for (int r = 0; r < 4; ++r)
            Os[(lg * 4 + r) * 260 + n] = oacc[nt][r] + bias;
    }
    __syncthreads();

    // ---- COALESCED out writeout: 16 rows x 256 f32 ----
#pragma unroll
    for (int i = 0; i < 4; ++i) {
        const int g = i * 256 + tid;
        const int row = g >> 6, u = g & 63;
        float4 v = *reinterpret_cast<const float4*>(&Os[row * 260 + u * 4]);
        *reinterpret_cast<float4*>(out + ((size_t)b * SS + q0 + row) * HIDD + u * 4) = v;
    }
}

// ---------------------------------------------------------------------------
extern "C" void kernel_launch(void* const* d_in, const int* in_sizes, int n_in,
                              void* d_out, int out_size, void* d_ws, size_t ws_size,
                              hipStream_t stream)
{
    const float* query = (const float*)d_in[0];
    const float* key   = (const float*)d_in[1];
    const float* value = (const float*)d_in[2];
    const int*   mask  = (const int*)d_in[3];
    const float* Wq = (const float*)d_in[4];
    const float* bq = (const float*)d_in[5];
    const float* Wk = (const float*)d_in[6];
    const float* bk = (const float*)d_in[7];
    const float* Wv = (const float*)d_in[8];
    const float* bv = (const float*)d_in[9];
    const float* Wh = (const float*)d_in[10];
    const float* bh = (const float*)d_in[11];

    float* out  = (float*)d_out;                       // [B,S,HID]
    float* attn = out + (size_t)NB * SS * HIDD;        // [B,S,S]

    const size_t BS = (size_t)NB * SS;
    short* Qhi = (short*)d_ws;                         // frag-tiled [b][h][t16][ks2][64][8]
    short* Khi = Qhi + BS * HIDD;
    short* VT  = Khi + BS * HIDD;                      // [b][4][16][64][8] bf16
    short* WhT = VT + BS * ADIM;                       // [256][64] bf16

    // WT lives at the head of the attn output region; qkv kernels consume it
    // before attn_probs_fused overwrites that region. 576*256*2 shorts = 590KB.
    short* WT_hi = (short*)attn;
    short* WT_lo = WT_hi + NTOT * HIDD;

    prep_weights<<<dim3(NTOT + 64), 256, 0, stream>>>(Wq, Wk, Wv, Wh,
                                                      WT_hi, WT_lo, WhT);
    qkv_qk<<<dim3(512, 4), 256, 0, stream>>>(query, key, WT_hi, WT_lo,
                                             bq, bk, Qhi, Khi);
    qkv_v<<<dim3(512), 256, 0, stream>>>(value, WT_hi, WT_lo, bv, VT);
    attn_probs_fused<<<dim3(2048), 256, 0, stream>>>(Qhi, Khi, VT, WhT,
                                                     mask, bh, attn, out);
}

// Round 21
// 134.827 us; speedup vs baseline: 1.0925x; 1.0925x over previous
//
#include <hip/hip_runtime.h>

#define NB 64
#define SS 512
#define HIDD 256
#define NHEADS 4
#define ADIM 64
#define NTOT 576   // Wq(256) + Wk(256) + Wv(64) concatenated output cols

typedef __attribute__((ext_vector_type(8))) short short8v;
typedef __attribute__((ext_vector_type(4))) float f32x4;

#define MFMA16(A, B, C) __builtin_amdgcn_mfma_f32_16x16x32_bf16(A, B, C, 0, 0, 0)
#define AS1 __attribute__((address_space(1)))
#define AS3 __attribute__((address_space(3)))

// async 16B/lane global->LDS copy (dest = wave-uniform base + lane*16)
__device__ __forceinline__ void g2l16(void* lds, const void* g) {
    __builtin_amdgcn_global_load_lds((const AS1 unsigned*)g,
                                     (AS3 unsigned*)lds, 16, 0, 0);
}

// split fp32 x into bf16 hi + bf16 lo with x ~= hi + lo (error ~2^-17 rel)
__device__ __forceinline__ void bsplit(float x, short& hi, short& lo) {
    unsigned u = __float_as_uint(x);
    unsigned uh = (u + 0x8000u) & 0xFFFF0000u;
    hi = (short)(uh >> 16);
    float r = x - __uint_as_float(uh);
    lo = (short)((__float_as_uint(r) + 0x8000u) >> 16);
}

__device__ __forceinline__ void bsplit_v(float x, short8v& vh, short8v& vl, int i) {
    short h, l;
    bsplit(x, h, l);
    vh[i] = h;
    vl[i] = l;
}

// round-to-nearest fp32 -> bf16 (single)
__device__ __forceinline__ short bf16r(float x) {
    return (short)((__float_as_uint(x) + 0x8000u) >> 16);
}

// fragment-tiled Q/K address: [b][h][t16][ks2][lane][8], lane = rk + 16*lgk
__device__ __forceinline__ int frag_addr(int bb, int hh, int s, int d) {
    const int t16 = s >> 4, rk = s & 15;
    const int ks2 = d >> 5, lgk = (d >> 3) & 3, e8 = d & 7;
    return ((((bb * 4 + hh) * 32 + t16) * 2 + ks2) * 64 + rk + 16 * lgk) * 8 + e8;
}

// ---------------------------------------------------------------------------
// Pre-split + transpose weights. Blocks 0..575: WT[n][k] hi/lo for {Wq|Wk|Wv}.
// Blocks 576..639: WhT[n][d] single-bf16 (Wh transposed).
// ---------------------------------------------------------------------------
__global__ __launch_bounds__(256) void prep_weights(
    const float* __restrict__ Wq, const float* __restrict__ Wk,
    const float* __restrict__ Wv, const float* __restrict__ Wh,
    short* __restrict__ WT_hi, short* __restrict__ WT_lo,
    short* __restrict__ WhT)
{
    const int bx = blockIdx.x;
    if (bx < NTOT) {
        const int idx = bx * 256 + threadIdx.x;   // 576*256 elements
        const int n = idx >> 8, k = idx & 255;
        float v;
        if (n < 256)      v = Wq[k * 256 + n];
        else if (n < 512) v = Wk[k * 256 + (n - 256)];
        else              v = Wv[k * 64 + (n - 512)];
        short h, l;
        bsplit(v, h, l);
        WT_hi[idx] = h;
        WT_lo[idx] = l;
    } else {
        const int idx2 = (bx - NTOT) * 256 + threadIdx.x;  // 256*64 elements
        const int n = idx2 >> 6, d = idx2 & 63;
        WhT[idx2] = bf16r(Wh[d * HIDD + n]);
    }
}

// ---------------------------------------------------------------------------
// Merged Q/K/V projection (MFMA split-bf16, 3-term internally).
// y = {0,1} Q halves, {2,3} K halves (64m x 128n, frag-tile bf16 out);
// y = 4     V          (64m x 64n, V^T frag-tile bf16 out).
// A-frags in registers (prefetched); WT chunk dbuf LDS-DMA staging.
// ---------------------------------------------------------------------------
__global__ __launch_bounds__(256) void qkv_proj(
    const float* __restrict__ query, const float* __restrict__ key,
    const float* __restrict__ value,
    const short* __restrict__ WT_hi, const short* __restrict__ WT_lo,
    const float* __restrict__ bq, const float* __restrict__ bk,
    const float* __restrict__ bv,
    short* __restrict__ Qhi, short* __restrict__ Khi,
    short* __restrict__ VT)
{
    __shared__ short Ws_h[2][128 * 32];   // 8 KB per buffer (V path uses 1/2)
    __shared__ short Ws_l[2][128 * 32];   // 8 KB per buffer

    const int bm = blockIdx.x * 64;
    const int y = blockIdx.y;             // 0,1 Q halves; 2,3 K halves; 4 V
    const bool isV = (y == 4);
    const int t = y >> 1;                 // 0 = Q, 1 = K (when !isV)
    const int half = y & 1;
    const int nrow0 = isV ? 512 : (t * 256 + half * 128);
    const float* A = isV ? value : (t ? key : query);
    const float* biasp = isV ? bv : (t ? bk : bq);
    short* Dhi = t ? Khi : Qhi;           // unused when isV

    const int tid = threadIdx.x;
    const int w = tid >> 6, l = tid & 63;
    const int l15 = l & 15, lg = l >> 4;
    const int wbase = tid & 192;          // wave-uniform

    const int NJ = isV ? 4 : 8;           // n-subtiles

    auto stageWT = [&](int buf, int kc) {
        if (isV) {
            const int row = tid >> 2;             // 0..63
            const int p = tid & 3;
            const int sl = p ^ (row & 3);
            const size_t goff = (size_t)(nrow0 + row) * HIDD + kc * 32 + sl * 8;
            g2l16(&Ws_h[buf][wbase * 8], WT_hi + goff);
            g2l16(&Ws_l[buf][wbase * 8], WT_lo + goff);
        } else {
#pragma unroll
            for (int i = 0; i < 2; ++i) {
                const int g = i * 256 + tid;          // chunk id 0..511
                const int row = g >> 2;               // 0..127
                const int p = g & 3;
                const int sl = p ^ (row & 3);
                const size_t goff = (size_t)(nrow0 + row) * HIDD + kc * 32 + sl * 8;
                g2l16(&Ws_h[buf][(i * 256 + wbase) * 8], WT_hi + goff);
                g2l16(&Ws_l[buf][(i * 256 + wbase) * 8], WT_lo + goff);
            }
        }
    };

    const float* arow = A + (size_t)(bm + w * 16 + l15) * HIDD + lg * 8;

    f32x4 acc[8];
#pragma unroll
    for (int jn = 0; jn < 8; ++jn) acc[jn] = (f32x4){0.f, 0.f, 0.f, 0.f};

    float4 a0c = *reinterpret_cast<const float4*>(arow);
    float4 a1c = *reinterpret_cast<const float4*>(arow + 4);
    stageWT(0, 0);
    __syncthreads();   // WT[0] ready (vmcnt drained)

    int cur = 0;
#pragma unroll
    for (int kc = 0; kc < 8; ++kc) {
        float4 a0n, a1n;
        if (kc < 7) {
            a0n = *reinterpret_cast<const float4*>(arow + (kc + 1) * 32);
            a1n = *reinterpret_cast<const float4*>(arow + (kc + 1) * 32 + 4);
            stageWT(cur ^ 1, kc + 1);   // DMA overlaps this iter's compute
        }

        short8v ah, al;
        bsplit_v(a0c.x, ah, al, 0);
        bsplit_v(a0c.y, ah, al, 1);
        bsplit_v(a0c.z, ah, al, 2);
        bsplit_v(a0c.w, ah, al, 3);
        bsplit_v(a1c.x, ah, al, 4);
        bsplit_v(a1c.y, ah, al, 5);
        bsplit_v(a1c.z, ah, al, 6);
        bsplit_v(a1c.w, ah, al, 7);

        for (int jn = 0; jn < NJ; ++jn) {
            const int rowB = jn * 16 + l15;
            const int c = lg ^ (rowB & 3);
            short8v bh = *reinterpret_cast<const short8v*>(&Ws_h[cur][rowB * 32 + c * 8]);
            short8v bl = *reinterpret_cast<const short8v*>(&Ws_l[cur][rowB * 32 + c * 8]);
            acc[jn] = MFMA16(ah, bh, acc[jn]);
            acc[jn] = MFMA16(ah, bl, acc[jn]);
            acc[jn] = MFMA16(al, bh, acc[jn]);
        }
        __syncthreads();   // readers done with cur; prefetch landed
        cur ^= 1;
        if (kc < 7) { a0c = a0n; a1c = a1n; }
    }

    // ---- epilogue ----
    if (!isV) {
        // Q/K: bias + fragment-tiled single-bf16 scatter
#pragma unroll
        for (int jn = 0; jn < 8; ++jn) {
            const int ncol = half * 128 + jn * 16 + l15;   // 0..255 within tensor
            const float bias = biasp[ncol];
            const int hh = ncol >> 6, dd = ncol & 63;
#pragma unroll
            for (int r = 0; r < 4; ++r) {
                const int m = bm + w * 16 + lg * 4 + r;
                const int bb = m >> 9, s = m & 511;
                const int fa = frag_addr(bb, hh, s, dd);
                Dhi[fa] = bf16r(acc[jn][r] + bias);
            }
        }
    } else {
        // V: V^T bf16 frag-tile scatter
#pragma unroll
        for (int jn = 0; jn < 4; ++jn) {
            const int d = jn * 16 + l15;
            const float bias = biasp[d];
#pragma unroll
            for (int r = 0; r < 4; ++r) {
                const int m = bm + w * 16 + lg * 4 + r;
                const int bb = m >> 9, kk = m & 511;
                const int ks = kk >> 5;
                const int lane = l15 + 16 * ((kk >> 3) & 3);
                const int idx = (((bb * 4 + jn) * 16 + ks) * 64 + lane) * 8 + (kk & 7);
                VT[idx] = bf16r(acc[jn][r] + bias);
            }
        }
    }
}

// ---------------------------------------------------------------------------
// FUSED attention, 4 waves x 16 q-rows (2048 blocks). Wave w owns k-quarter
// kt = w. r19 build (best measured): compiler-scheduled loads (VGPR 60,
// high occupancy), coalesced LDS-staged writeout for attn and out.
// QK^T single bf16.
// ---------------------------------------------------------------------------
__global__ __launch_bounds__(256) void attn_probs_fused(
    const short* __restrict__ Qhi_g, const short* __restrict__ Khi_g,
    const short* __restrict__ VT, const short* __restrict__ WhT,
    const int* __restrict__ mask, const float* __restrict__ bh,
    float* __restrict__ attn, float* __restrict__ out)
{
    __shared__ __align__(16) float As[16 * 516];   // 33KB attn tile; aliased later
    __shared__ float red[2][4][16];

    // bijective XCD swizzle: 2048 blocks = 8 xcds x 256
    const int wg = blockIdx.x;
    const int swz = (wg & 7) * 256 + (wg >> 3);
    const int b = swz >> 5;
    const int qt_base = swz & 31;         // q-tile16 index
    const int q0 = qt_base * 16;

    const int tid = threadIdx.x;
    const int w = tid >> 6;               // 0..3 -> k-quarter kt = w
    const int l = tid & 63;
    const int l15 = l & 15;
    const int lg = l >> 4;

    // ---- pack mask bits: lane row q0+l15; 8 subtiles x 4 k-bits = 32 bits ----
    unsigned mbits = 0;
    {
        const int q = q0 + l15;
        const int* mrow = mask + ((size_t)b * SS + q) * SS;
#pragma unroll
        for (int ms = 0; ms < 8; ++ms) {
            const int k = w * 128 + ms * 16 + lg * 4;
            int4 mv = *reinterpret_cast<const int4*>(&mrow[k]);
            mbits |= (mv.x != 0 ? 1u : 0u) << (ms * 4 + 0);
            mbits |= (mv.y != 0 ? 1u : 0u) << (ms * 4 + 1);
            mbits |= (mv.z != 0 ? 1u : 0u) << (ms * 4 + 2);
            mbits |= (mv.w != 0 ? 1u : 0u) << (ms * 4 + 3);
        }
    }

    f32x4 acc[8];
#pragma unroll
    for (int ms = 0; ms < 8; ++ms) acc[ms] = (f32x4){0.f, 0.f, 0.f, 0.f};

    for (int h = 0; h < NHEADS; ++h) {
        const int bh32 = (b * 4 + h) * 32;

        // ---- Q fragments (hi only): coalesced frag-tile loads ----
        short8v qh[2];
#pragma unroll
        for (int ks2 = 0; ks2 < 2; ++ks2) {
            const int off = (((bh32 + qt_base) * 2 + ks2) * 64 + l) * 8;
            qh[ks2] = *reinterpret_cast<const short8v*>(Qhi_g + off);
        }

        f32x4 e[8];
#pragma unroll
        for (int ms = 0; ms < 8; ++ms) e[ms] = (f32x4){0.f, 0.f, 0.f, 0.f};

#pragma unroll
        for (int ms = 0; ms < 8; ++ms) {
            const int t16 = w * 8 + ms;
#pragma unroll
            for (int ks2 = 0; ks2 < 2; ++ks2) {
                const int base = (((bh32 + t16) * 2 + ks2) * 64 + l) * 8;
                short8v ah = *reinterpret_cast<const short8v*>(Khi_g + base);
                e[ms] = MFMA16(ah, qh[ks2], e[ms]);
            }
        }

        // ---- masked exp (no max shift) + sum + head-mean accumulate ----
        float sm = 0.f;
        const float c = 0.125f;
#pragma unroll
        for (int ms = 0; ms < 8; ++ms)
#pragma unroll
            for (int r = 0; r < 4; ++r) {
                float p = __expf(e[ms][r] * c);
                const unsigned bit = (mbits >> (ms * 4 + r)) & 1u;
                p = bit ? p : 0.f;
                e[ms][r] = p;
                sm += p;
            }
        sm += __shfl_xor(sm, 16);
        sm += __shfl_xor(sm, 32);
        if (l < 16) red[h & 1][w][l] = sm;
        __syncthreads();
        {
            const float Z = (red[h & 1][0][l15] + red[h & 1][1][l15]) +
                            (red[h & 1][2][l15] + red[h & 1][3][l15]);
            const float inv = 0.25f / fmaxf(Z, 1e-30f);
#pragma unroll
            for (int ms = 0; ms < 8; ++ms)
#pragma unroll
                for (int r = 0; r < 4; ++r)
                    acc[ms][r] += e[ms][r] * inv;
        }
    }

    // ---- stage attn tile in LDS (f32) ----
#pragma unroll
    for (int ms = 0; ms < 8; ++ms) {
        const int k = w * 128 + ms * 16 + lg * 4;
        float4 o;
        o.x = acc[ms][0];
        o.y = acc[ms][1];
        o.z = acc[ms][2];
        o.w = acc[ms][3];
        *reinterpret_cast<float4*>(&As[l15 * 516 + k]) = o;
    }
    __syncthreads();

    // ---- COALESCED attn writeout: 16 rows x 512 f32, 16B/lane linear ----
    {
        float* attn_base = attn + ((size_t)b * SS + q0) * SS;
#pragma unroll
        for (int i = 0; i < 8; ++i) {
            const int g = i * 256 + tid;
            const int row = g >> 7, u = g & 127;
            float4 v = *reinterpret_cast<const float4*>(&As[row * 516 + u * 4]);
            *reinterpret_cast<float4*>(attn_base + (size_t)row * SS + u * 4) = v;
        }
    }

    // ---- PV: T^T[d][q] = sum_k V^T[d][k] P[k][q]; wave w owns d-tile w ----
    f32x4 tacc = (f32x4){0.f, 0.f, 0.f, 0.f};
#pragma unroll
    for (int ks = 0; ks < 16; ++ks) {
        short8v va = *reinterpret_cast<const short8v*>(
            VT + (((b * 4 + w) * 16 + ks) * 64 + l) * 8);
        float4 p0 = *reinterpret_cast<const float4*>(&As[l15 * 516 + ks * 32 + lg * 8]);
        float4 p1 = *reinterpret_cast<const float4*>(&As[l15 * 516 + ks * 32 + lg * 8 + 4]);
        short8v pb;
        pb[0] = bf16r(p0.x);
        pb[1] = bf16r(p0.y);
        pb[2] = bf16r(p0.z);
        pb[3] = bf16r(p0.w);
        pb[4] = bf16r(p1.x);
        pb[5] = bf16r(p1.y);
        pb[6] = bf16r(p1.z);
        pb[7] = bf16r(p1.w);
        tacc = MFMA16(va, pb, tacc);
    }
    __syncthreads();   // all As reads done before aliasing as T_s

    // ---- T -> LDS f32 (alias of As): T_s[q][68], q 0..15, d 0..63 ----
    float* T_s = As;
    {
        const int q = l15;
        const int d = w * 16 + lg * 4;
        float4 tv;
        tv.x = tacc[0];
        tv.y = tacc[1];
        tv.z = tacc[2];
        tv.w = tacc[3];
        *reinterpret_cast<float4*>(&T_s[q * 68 + d]) = tv;
    }
    __syncthreads();

    // ---- TWh: out[q][n] = sum_d T[q][d] Wh[d][n] + bh; wave w: n-tiles 4w..4w+3
    f32x4 oacc[4];
#pragma unroll
    for (int nt = 0; nt < 4; ++nt) oacc[nt] = (f32x4){0.f, 0.f, 0.f, 0.f};

#pragma unroll
    for (int ks = 0; ks < 2; ++ks) {
        short8v ta;
        {
            const int q = l15;
            float4 t0 = *reinterpret_cast<const float4*>(&T_s[q * 68 + ks * 32 + lg * 8]);
            float4 t1 = *reinterpret_cast<const float4*>(&T_s[q * 68 + ks * 32 + lg * 8 + 4]);
            ta[0] = bf16r(t0.x);
            ta[1] = bf16r(t0.y);
            ta[2] = bf16r(t0.z);
            ta[3] = bf16r(t0.w);
            ta[4] = bf16r(t1.x);
            ta[5] = bf16r(t1.y);
            ta[6] = bf16r(t1.z);
            ta[7] = bf16r(t1.w);
        }
#pragma unroll
        for (int nt = 0; nt < 4; ++nt) {
            const int n = (w * 4 + nt) * 16 + l15;
            short8v wb = *reinterpret_cast<const short8v*>(
                WhT + n * 64 + ks * 32 + lg * 8);
            oacc[nt] = MFMA16(ta, wb, oacc[nt]);
        }
    }

    // ---- stage out tile (with bias) in LDS: Os[q][260] at As+1536 ----
    float* Os = As + 1536;   // past T_s region (1088 floats), 16B aligned
#pragma unroll
    for (int nt = 0; nt < 4; ++nt) {
        const int n = (w * 4 + nt) * 16 + l15;
        const float bias = bh[n];
#pragma unroll
        for (int r = 0; r < 4; ++r)
            Os[(lg * 4 + r) * 260 + n] = oacc[nt][r] + bias;
    }
    __syncthreads();

    // ---- COALESCED out writeout: 16 rows x 256 f32 ----
#pragma unroll
    for (int i = 0; i < 4; ++i) {
        const int g = i * 256 + tid;
        const int row = g >> 6, u = g & 63;
        float4 v = *reinterpret_cast<const float4*>(&Os[row * 260 + u * 4]);
        *reinterpret_cast<float4*>(out + ((size_t)b * SS + q0 + row) * HIDD + u * 4) = v;
    }
}

// ---------------------------------------------------------------------------
extern "C" void kernel_launch(void* const* d_in, const int* in_sizes, int n_in,
                              void* d_out, int out_size, void* d_ws, size_t ws_size,
                              hipStream_t stream)
{
    const float* query = (const float*)d_in[0];
    const float* key   = (const float*)d_in[1];
    const float* value = (const float*)d_in[2];
    const int*   mask  = (const int*)d_in[3];
    const float* Wq = (const float*)d_in[4];
    const float* bq = (const float*)d_in[5];
    const float* Wk = (const float*)d_in[6];
    const float* bk = (const float*)d_in[7];
    const float* Wv = (const float*)d_in[8];
    const float* bv = (const float*)d_in[9];
    const float* Wh = (const float*)d_in[10];
    const float* bh = (const float*)d_in[11];

    float* out  = (float*)d_out;                       // [B,S,HID]
    float* attn = out + (size_t)NB * SS * HIDD;        // [B,S,S]

    const size_t BS = (size_t)NB * SS;
    short* Qhi = (short*)d_ws;                         // frag-tiled [b][h][t16][ks2][64][8]
    short* Khi = Qhi + BS * HIDD;
    short* VT  = Khi + BS * HIDD;                      // [b][4][16][64][8] bf16
    short* WhT = VT + BS * ADIM;                       // [256][64] bf16

    // WT lives at the head of the attn output region; qkv kernels consume it
    // before attn_probs_fused overwrites that region. 576*256*2 shorts = 590KB.
    short* WT_hi = (short*)attn;
    short* WT_lo = WT_hi + NTOT * HIDD;

    prep_weights<<<dim3(NTOT + 64), 256, 0, stream>>>(Wq, Wk, Wv, Wh,
                                                      WT_hi, WT_lo, WhT);
    qkv_proj<<<dim3(512, 5), 256, 0, stream>>>(query, key, value, WT_hi, WT_lo,
                                               bq, bk, bv, Qhi, Khi, VT);
    attn_probs_fused<<<dim3(2048), 256, 0, stream>>>(Qhi, Khi, VT, WhT,
                                                     mask, bh, attn, out);
}

// Round 22
// 130.765 us; speedup vs baseline: 1.1264x; 1.0311x over previous
//
#include <hip/hip_runtime.h>

#define NB 64
#define SS 512
#define HIDD 256
#define NHEADS 4
#define ADIM 64
#define NTOT 576   // Wq(256) + Wk(256) + Wv(64) concatenated output cols

typedef __attribute__((ext_vector_type(8))) short short8v;
typedef __attribute__((ext_vector_type(4))) float f32x4;

#define MFMA16(A, B, C) __builtin_amdgcn_mfma_f32_16x16x32_bf16(A, B, C, 0, 0, 0)
#define AS1 __attribute__((address_space(1)))
#define AS3 __attribute__((address_space(3)))

// async 16B/lane global->LDS copy (dest = wave-uniform base + lane*16)
__device__ __forceinline__ void g2l16(void* lds, const void* g) {
    __builtin_amdgcn_global_load_lds((const AS1 unsigned*)g,
                                     (AS3 unsigned*)lds, 16, 0, 0);
}

// split fp32 x into bf16 hi + bf16 lo with x ~= hi + lo (error ~2^-17 rel)
__device__ __forceinline__ void bsplit(float x, short& hi, short& lo) {
    unsigned u = __float_as_uint(x);
    unsigned uh = (u + 0x8000u) & 0xFFFF0000u;
    hi = (short)(uh >> 16);
    float r = x - __uint_as_float(uh);
    lo = (short)((__float_as_uint(r) + 0x8000u) >> 16);
}

__device__ __forceinline__ void bsplit_v(float x, short8v& vh, short8v& vl, int i) {
    short h, l;
    bsplit(x, h, l);
    vh[i] = h;
    vl[i] = l;
}

// round-to-nearest fp32 -> bf16 (single)
__device__ __forceinline__ short bf16r(float x) {
    return (short)((__float_as_uint(x) + 0x8000u) >> 16);
}

// fragment-tiled Q/K address: [b][h][t16][ks2][lane][8], lane = rk + 16*lgk
__device__ __forceinline__ int frag_addr(int bb, int hh, int s, int d) {
    const int t16 = s >> 4, rk = s & 15;
    const int ks2 = d >> 5, lgk = (d >> 3) & 3, e8 = d & 7;
    return ((((bb * 4 + hh) * 32 + t16) * 2 + ks2) * 64 + rk + 16 * lgk) * 8 + e8;
}

// ---------------------------------------------------------------------------
// Pre-split + transpose weights. Blocks 0..575: WT[n][k] hi/lo for {Wq|Wk|Wv}.
// Blocks 576..639: WhT[n][d] single-bf16 (Wh transposed).
// ---------------------------------------------------------------------------
__global__ __launch_bounds__(256) void prep_weights(
    const float* __restrict__ Wq, const float* __restrict__ Wk,
    const float* __restrict__ Wv, const float* __restrict__ Wh,
    short* __restrict__ WT_hi, short* __restrict__ WT_lo,
    short* __restrict__ WhT)
{
    const int bx = blockIdx.x;
    if (bx < NTOT) {
        const int idx = bx * 256 + threadIdx.x;   // 576*256 elements
        const int n = idx >> 8, k = idx & 255;
        float v;
        if (n < 256)      v = Wq[k * 256 + n];
        else if (n < 512) v = Wk[k * 256 + (n - 256)];
        else              v = Wv[k * 64 + (n - 512)];
        short h, l;
        bsplit(v, h, l);
        WT_hi[idx] = h;
        WT_lo[idx] = l;
    } else {
        const int idx2 = (bx - NTOT) * 256 + threadIdx.x;  // 256*64 elements
        const int n = idx2 >> 6, d = idx2 & 63;
        WhT[idx2] = bf16r(Wh[d * HIDD + n]);
    }
}

// ---------------------------------------------------------------------------
// Q/K projection (MFMA split-bf16, 3-term internally). Block = 64 m-rows x
// 128 n-cols: y = {0,1} -> Q halves, {2,3} -> K halves. LDS 32KB (4 blk/CU).
// A-frags in registers (prefetched); WT chunk (128x32 hi+lo) dbuf LDS-DMA.
// Output: single-bf16 frag tiles (QK^T consumer is single-bf16).
// ---------------------------------------------------------------------------
__global__ __launch_bounds__(256) void qkv_qk(
    const float* __restrict__ query, const float* __restrict__ key,
    const short* __restrict__ WT_hi, const short* __restrict__ WT_lo,
    const float* __restrict__ bq, const float* __restrict__ bk,
    short* __restrict__ Qhi, short* __restrict__ Khi)
{
    __shared__ short Ws_h[2][128 * 32];   // 8 KB per buffer
    __shared__ short Ws_l[2][128 * 32];   // 8 KB per buffer

    const int bm = blockIdx.x * 64;
    const int y = blockIdx.y;             // 0,1 = Q halves; 2,3 = K halves
    const int t = y >> 1;                 // 0 = Q, 1 = K
    const int half = y & 1;
    const int nrow0 = t * 256 + half * 128;   // row base in WT
    const float* A = t ? key : query;
    const float* biasp = t ? bk : bq;
    short* Dhi = t ? Khi : Qhi;

    const int tid = threadIdx.x;
    const int w = tid >> 6, l = tid & 63;
    const int l15 = l & 15, lg = l >> 4;
    const int wbase = tid & 192;          // wave-uniform

    auto stageWT = [&](int buf, int kc) {
#pragma unroll
        for (int i = 0; i < 2; ++i) {
            const int g = i * 256 + tid;          // chunk id 0..511
            const int row = g >> 2;               // 0..127
            const int p = g & 3;
            const int sl = p ^ (row & 3);
            const size_t goff = (size_t)(nrow0 + row) * HIDD + kc * 32 + sl * 8;
            g2l16(&Ws_h[buf][(i * 256 + wbase) * 8], WT_hi + goff);
            g2l16(&Ws_l[buf][(i * 256 + wbase) * 8], WT_lo + goff);
        }
    };

    const float* arow = A + (size_t)(bm + w * 16 + l15) * HIDD + lg * 8;

    f32x4 acc[8];
#pragma unroll
    for (int jn = 0; jn < 8; ++jn) acc[jn] = (f32x4){0.f, 0.f, 0.f, 0.f};

    float4 a0c = *reinterpret_cast<const float4*>(arow);
    float4 a1c = *reinterpret_cast<const float4*>(arow + 4);
    stageWT(0, 0);
    __syncthreads();   // WT[0] ready (vmcnt drained)

    int cur = 0;
#pragma unroll
    for (int kc = 0; kc < 8; ++kc) {
        float4 a0n, a1n;
        if (kc < 7) {
            a0n = *reinterpret_cast<const float4*>(arow + (kc + 1) * 32);
            a1n = *reinterpret_cast<const float4*>(arow + (kc + 1) * 32 + 4);
            stageWT(cur ^ 1, kc + 1);   // DMA overlaps this iter's compute
        }

        short8v ah, al;
        bsplit_v(a0c.x, ah, al, 0);
        bsplit_v(a0c.y, ah, al, 1);
        bsplit_v(a0c.z, ah, al, 2);
        bsplit_v(a0c.w, ah, al, 3);
        bsplit_v(a1c.x, ah, al, 4);
        bsplit_v(a1c.y, ah, al, 5);
        bsplit_v(a1c.z, ah, al, 6);
        bsplit_v(a1c.w, ah, al, 7);

#pragma unroll
        for (int jn = 0; jn < 8; ++jn) {
            const int rowB = jn * 16 + l15;
            const int c = lg ^ (rowB & 3);
            short8v bh = *reinterpret_cast<const short8v*>(&Ws_h[cur][rowB * 32 + c * 8]);
            short8v bl = *reinterpret_cast<const short8v*>(&Ws_l[cur][rowB * 32 + c * 8]);
            acc[jn] = MFMA16(ah, bh, acc[jn]);
            acc[jn] = MFMA16(ah, bl, acc[jn]);
            acc[jn] = MFMA16(al, bh, acc[jn]);
        }
        __syncthreads();   // readers done with cur; prefetch landed
        cur ^= 1;
        if (kc < 7) { a0c = a0n; a1c = a1n; }
    }

    // ---- epilogue: bias + fragment-tiled single-bf16 scatter ----
#pragma unroll
    for (int jn = 0; jn < 8; ++jn) {
        const int ncol = half * 128 + jn * 16 + l15;   // 0..255 within tensor
        const float bias = biasp[ncol];
        const int hh = ncol >> 6, dd = ncol & 63;
#pragma unroll
        for (int r = 0; r < 4; ++r) {
            const int m = bm + w * 16 + lg * 4 + r;
            const int bb = m >> 9, s = m & 511;
            const int fa = frag_addr(bb, hh, s, dd);
            Dhi[fa] = bf16r(acc[jn][r] + bias);
        }
    }
}

// ---------------------------------------------------------------------------
// V projection -> V^T bf16 fragment tiles: VT[b][dt(4)][ks(16)][lane(64)][8]
// ---------------------------------------------------------------------------
__global__ __launch_bounds__(256) void qkv_v(
    const float* __restrict__ value,
    const short* __restrict__ WT_hi, const short* __restrict__ WT_lo,
    const float* __restrict__ bv, short* __restrict__ VT)
{
    __shared__ short Ws_h[2][64 * 32];    // 4 KB per buffer
    __shared__ short Ws_l[2][64 * 32];

    const int bm = blockIdx.x * 64;
    const int tid = threadIdx.x;
    const int w = tid >> 6, l = tid & 63;
    const int l15 = l & 15, lg = l >> 4;
    const int wbase = tid & 192;

    auto stageWT = [&](int buf, int kc) {
        const int row = tid >> 2;             // 0..63
        const int p = tid & 3;
        const int sl = p ^ (row & 3);
        const size_t goff = (size_t)(512 + row) * HIDD + kc * 32 + sl * 8;
        g2l16(&Ws_h[buf][wbase * 8], WT_hi + goff);
        g2l16(&Ws_l[buf][wbase * 8], WT_lo + goff);
    };

    const float* arow = value + (size_t)(bm + w * 16 + l15) * HIDD + lg * 8;

    f32x4 acc[4];
#pragma unroll
    for (int jn = 0; jn < 4; ++jn) acc[jn] = (f32x4){0.f, 0.f, 0.f, 0.f};

    float4 a0c = *reinterpret_cast<const float4*>(arow);
    float4 a1c = *reinterpret_cast<const float4*>(arow + 4);
    stageWT(0, 0);
    __syncthreads();

    int cur = 0;
#pragma unroll
    for (int kc = 0; kc < 8; ++kc) {
        float4 a0n, a1n;
        if (kc < 7) {
            a0n = *reinterpret_cast<const float4*>(arow + (kc + 1) * 32);
            a1n = *reinterpret_cast<const float4*>(arow + (kc + 1) * 32 + 4);
            stageWT(cur ^ 1, kc + 1);
        }

        short8v ah, al;
        bsplit_v(a0c.x, ah, al, 0);
        bsplit_v(a0c.y, ah, al, 1);
        bsplit_v(a0c.z, ah, al, 2);
        bsplit_v(a0c.w, ah, al, 3);
        bsplit_v(a1c.x, ah, al, 4);
        bsplit_v(a1c.y, ah, al, 5);
        bsplit_v(a1c.z, ah, al, 6);
        bsplit_v(a1c.w, ah, al, 7);

#pragma unroll
        for (int jn = 0; jn < 4; ++jn) {
            const int rowB = jn * 16 + l15;
            const int c = lg ^ (rowB & 3);
            short8v bh = *reinterpret_cast<const short8v*>(&Ws_h[cur][rowB * 32 + c * 8]);
            short8v bl = *reinterpret_cast<const short8v*>(&Ws_l[cur][rowB * 32 + c * 8]);
            acc[jn] = MFMA16(ah, bh, acc[jn]);
            acc[jn] = MFMA16(ah, bl, acc[jn]);
            acc[jn] = MFMA16(al, bh, acc[jn]);
        }
        __syncthreads();
        cur ^= 1;
        if (kc < 7) { a0c = a0n; a1c = a1n; }
    }

    // ---- epilogue: V^T bf16 frag-tile scatter ----
#pragma unroll
    for (int jn = 0; jn < 4; ++jn) {
        const int d = jn * 16 + l15;
        const float bias = bv[d];
#pragma unroll
        for (int r = 0; r < 4; ++r) {
            const int m = bm + w * 16 + lg * 4 + r;
            const int bb = m >> 9, kk = m & 511;
            const int ks = kk >> 5;
            const int lane = l15 + 16 * ((kk >> 3) & 3);
            const int idx = (((bb * 4 + jn) * 16 + ks) * 64 + lane) * 8 + (kk & 7);
            VT[idx] = bf16r(acc[jn][r] + bias);
        }
    }
}

// ---------------------------------------------------------------------------
// FUSED attention, 4 waves x 16 q-rows (2048 blocks). Wave w owns k-quarter
// kt = w. r19 build (best measured): compiler-scheduled loads (VGPR 60,
// high occupancy), coalesced LDS-staged writeout for attn and out.
// QK^T single bf16.
// ---------------------------------------------------------------------------
__global__ __launch_bounds__(256) void attn_probs_fused(
    const short* __restrict__ Qhi_g, const short* __restrict__ Khi_g,
    const short* __restrict__ VT, const short* __restrict__ WhT,
    const int* __restrict__ mask, const float* __restrict__ bh,
    float* __restrict__ attn, float* __restrict__ out)
{
    __shared__ __align__(16) float As[16 * 516];   // 33KB attn tile; aliased later
    __shared__ float red[2][4][16];

    // bijective XCD swizzle: 2048 blocks = 8 xcds x 256
    const int wg = blockIdx.x;
    const int swz = (wg & 7) * 256 + (wg >> 3);
    const int b = swz >> 5;
    const int qt_base = swz & 31;         // q-tile16 index
    const int q0 = qt_base * 16;

    const int tid = threadIdx.x;
    const int w = tid >> 6;               // 0..3 -> k-quarter kt = w
    const int l = tid & 63;
    const int l15 = l & 15;
    const int lg = l >> 4;

    // ---- pack mask bits: lane row q0+l15; 8 subtiles x 4 k-bits = 32 bits ----
    unsigned mbits = 0;
    {
        const int q = q0 + l15;
        const int* mrow = mask + ((size_t)b * SS + q) * SS;
#pragma unroll
        for (int ms = 0; ms < 8; ++ms) {
            const int k = w * 128 + ms * 16 + lg * 4;
            int4 mv = *reinterpret_cast<const int4*>(&mrow[k]);
            mbits |= (mv.x != 0 ? 1u : 0u) << (ms * 4 + 0);
            mbits |= (mv.y != 0 ? 1u : 0u) << (ms * 4 + 1);
            mbits |= (mv.z != 0 ? 1u : 0u) << (ms * 4 + 2);
            mbits |= (mv.w != 0 ? 1u : 0u) << (ms * 4 + 3);
        }
    }

    f32x4 acc[8];
#pragma unroll
    for (int ms = 0; ms < 8; ++ms) acc[ms] = (f32x4){0.f, 0.f, 0.f, 0.f};

    for (int h = 0; h < NHEADS; ++h) {
        const int bh32 = (b * 4 + h) * 32;

        // ---- Q fragments (hi only): coalesced frag-tile loads ----
        short8v qh[2];
#pragma unroll
        for (int ks2 = 0; ks2 < 2; ++ks2) {
            const int off = (((bh32 + qt_base) * 2 + ks2) * 64 + l) * 8;
            qh[ks2] = *reinterpret_cast<const short8v*>(Qhi_g + off);
        }

        f32x4 e[8];
#pragma unroll
        for (int ms = 0; ms < 8; ++ms) e[ms] = (f32x4){0.f, 0.f, 0.f, 0.f};

#pragma unroll
        for (int ms = 0; ms < 8; ++ms) {
            const int t16 = w * 8 + ms;
#pragma unroll
            for (int ks2 = 0; ks2 < 2; ++ks2) {
                const int base = (((bh32 + t16) * 2 + ks2) * 64 + l) * 8;
                short8v ah = *reinterpret_cast<const short8v*>(Khi_g + base);
                e[ms] = MFMA16(ah, qh[ks2], e[ms]);
            }
        }

        // ---- masked exp (no max shift) + sum + head-mean accumulate ----
        float sm = 0.f;
        const float c = 0.125f;
#pragma unroll
        for (int ms = 0; ms < 8; ++ms)
#pragma unroll
            for (int r = 0; r < 4; ++r) {
                float p = __expf(e[ms][r] * c);
                const unsigned bit = (mbits >> (ms * 4 + r)) & 1u;
                p = bit ? p : 0.f;
                e[ms][r] = p;
                sm += p;
            }
        sm += __shfl_xor(sm, 16);
        sm += __shfl_xor(sm, 32);
        if (l < 16) red[h & 1][w][l] = sm;
        __syncthreads();
        {
            const float Z = (red[h & 1][0][l15] + red[h & 1][1][l15]) +
                            (red[h & 1][2][l15] + red[h & 1][3][l15]);
            const float inv = 0.25f / fmaxf(Z, 1e-30f);
#pragma unroll
            for (int ms = 0; ms < 8; ++ms)
#pragma unroll
                for (int r = 0; r < 4; ++r)
                    acc[ms][r] += e[ms][r] * inv;
        }
    }

    // ---- stage attn tile in LDS (f32) ----
#pragma unroll
    for (int ms = 0; ms < 8; ++ms) {
        const int k = w * 128 + ms * 16 + lg * 4;
        float4 o;
        o.x = acc[ms][0];
        o.y = acc[ms][1];
        o.z = acc[ms][2];
        o.w = acc[ms][3];
        *reinterpret_cast<float4*>(&As[l15 * 516 + k]) = o;
    }
    __syncthreads();

    // ---- COALESCED attn writeout: 16 rows x 512 f32, 16B/lane linear ----
    {
        float* attn_base = attn + ((size_t)b * SS + q0) * SS;
#pragma unroll
        for (int i = 0; i < 8; ++i) {
            const int g = i * 256 + tid;
            const int row = g >> 7, u = g & 127;
            float4 v = *reinterpret_cast<const float4*>(&As[row * 516 + u * 4]);
            *reinterpret_cast<float4*>(attn_base + (size_t)row * SS + u * 4) = v;
        }
    }

    // ---- PV: T^T[d][q] = sum_k V^T[d][k] P[k][q]; wave w owns d-tile w ----
    f32x4 tacc = (f32x4){0.f, 0.f, 0.f, 0.f};
#pragma unroll
    for (int ks = 0; ks < 16; ++ks) {
        short8v va = *reinterpret_cast<const short8v*>(
            VT + (((b * 4 + w) * 16 + ks) * 64 + l) * 8);
        float4 p0 = *reinterpret_cast<const float4*>(&As[l15 * 516 + ks * 32 + lg * 8]);
        float4 p1 = *reinterpret_cast<const float4*>(&As[l15 * 516 + ks * 32 + lg * 8 + 4]);
        short8v pb;
        pb[0] = bf16r(p0.x);
        pb[1] = bf16r(p0.y);
        pb[2] = bf16r(p0.z);
        pb[3] = bf16r(p0.w);
        pb[4] = bf16r(p1.x);
        pb[5] = bf16r(p1.y);
        pb[6] = bf16r(p1.z);
        pb[7] = bf16r(p1.w);
        tacc = MFMA16(va, pb, tacc);
    }
    __syncthreads();   // all As reads done before aliasing as T_s

    // ---- T -> LDS f32 (alias of As): T_s[q][68], q 0..15, d 0..63 ----
    float* T_s = As;
    {
        const int q = l15;
        const int d = w * 16 + lg * 4;
        float4 tv;
        tv.x = tacc[0];
        tv.y = tacc[1];
        tv.z = tacc[2];
        tv.w = tacc[3];
        *reinterpret_cast<float4*>(&T_s[q * 68 + d]) = tv;
    }
    __syncthreads();

    // ---- TWh: out[q][n] = sum_d T[q][d] Wh[d][n] + bh; wave w: n-tiles 4w..4w+3
    f32x4 oacc[4];
#pragma unroll
    for (int nt = 0; nt < 4; ++nt) oacc[nt] = (f32x4){0.f, 0.f, 0.f, 0.f};

#pragma unroll
    for (int ks = 0; ks < 2; ++ks) {
        short8v ta;
        {
            const int q = l15;
            float4 t0 = *reinterpret_cast<const float4*>(&T_s[q * 68 + ks * 32 + lg * 8]);
            float4 t1 = *reinterpret_cast<const float4*>(&T_s[q * 68 + ks * 32 + lg * 8 + 4]);
            ta[0] = bf16r(t0.x);
            ta[1] = bf16r(t0.y);
            ta[2] = bf16r(t0.z);
            ta[3] = bf16r(t0.w);
            ta[4] = bf16r(t1.x);
            ta[5] = bf16r(t1.y);
            ta[6] = bf16r(t1.z);
            ta[7] = bf16r(t1.w);
        }
#pragma unroll
        for (int nt = 0; nt < 4; ++nt) {
            const int n = (w * 4 + nt) * 16 + l15;
            short8v wb = *reinterpret_cast<const short8v*>(
                WhT + n * 64 + ks * 32 + lg * 8);
            oacc[nt] = MFMA16(ta, wb, oacc[nt]);
        }
    }

    // ---- stage out tile (with bias) in LDS: Os[q][260] at As+1536 ----
    float* Os = As + 1536;   // past T_s region (1088 floats), 16B aligned
#pragma unroll
    for (int nt = 0; nt < 4; ++nt) {
        const int n = (w * 4 + nt) * 16 + l15;
        const float bias = bh[n];
#pragma unroll
        for (int r = 0; r < 4; ++r)
            Os[(lg * 4 + r) * 260 + n] = oacc[nt][r] + bias;
    }
    __syncthreads();

    // ---- COALESCED out writeout: 16 rows x 256 f32 ----
#pragma unroll
    for (int i = 0; i < 4; ++i) {
        const int g = i * 256 + tid;
        const int row = g >> 6, u = g & 63;
        float4 v = *reinterpret_cast<const float4*>(&Os[row * 260 + u * 4]);
        *reinterpret_cast<float4*>(out + ((size_t)b * SS + q0 + row) * HIDD + u * 4) = v;
    }
}

// ---------------------------------------------------------------------------
extern "C" void kernel_launch(void* const* d_in, const int* in_sizes, int n_in,
                              void* d_out, int out_size, void* d_ws, size_t ws_size,
                              hipStream_t stream)
{
    const float* query = (const float*)d_in[0];
    const float* key   = (const float*)d_in[1];
    const float* value = (const float*)d_in[2];
    const int*   mask  = (const int*)d_in[3];
    const float* Wq = (const float*)d_in[4];
    const float* bq = (const float*)d_in[5];
    const float* Wk = (const float*)d_in[6];
    const float* bk = (const float*)d_in[7];
    const float* Wv = (const float*)d_in[8];
    const float* bv = (const float*)d_in[9];
    const float* Wh = (const float*)d_in[10];
    const float* bh = (const float*)d_in[11];

    float* out  = (float*)d_out;                       // [B,S,HID]
    float* attn = out + (size_t)NB * SS * HIDD;        // [B,S,S]

    const size_t BS = (size_t)NB * SS;
    short* Qhi = (short*)d_ws;                         // frag-tiled [b][h][t16][ks2][64][8]
    short* Khi = Qhi + BS * HIDD;
    short* VT  = Khi + BS * HIDD;                      // [b][4][16][64][8] bf16
    short* WhT = VT + BS * ADIM;                       // [256][64] bf16

    // WT lives at the head of the attn output region; qkv kernels consume it
    // before attn_probs_fused overwrites that region. 576*256*2 shorts = 590KB.
    short* WT_hi = (short*)attn;
    short* WT_lo = WT_hi + NTOT * HIDD;

    prep_weights<<<dim3(NTOT + 64), 256, 0, stream>>>(Wq, Wk, Wv, Wh,
                                                      WT_hi, WT_lo, WhT);
    qkv_qk<<<dim3(512, 4), 256, 0, stream>>>(query, key, WT_hi, WT_lo,
                                             bq, bk, Qhi, Khi);
    qkv_v<<<dim3(512), 256, 0, stream>>>(value, WT_hi, WT_lo, bv, VT);
    attn_probs_fused<<<dim3(2048), 256, 0, stream>>>(Qhi, Khi, VT, WhT,
                                                     mask, bh, attn, out);
}